// Round 7
// baseline (14716.852 us; speedup 1.0000x reference)
//
#include <hip/hip_runtime.h>
#include <math.h>

#define BB 512     // batch
#define HH 1024    // hidden
#define OO 512     // output
#define KC 1536    // O + H
#define G4H 4096   // 4*H
#define TT 256     // out_len

typedef _Float16 half8 __attribute__((ext_vector_type(8)));
typedef float f32x4 __attribute__((ext_vector_type(4)));

// async global->LDS DMA, 16B/lane; LDS dest = wave-uniform base + lane*16
__device__ __forceinline__ void dma16(const void* g, void* l) {
    __builtin_amdgcn_global_load_lds(
        (const __attribute__((address_space(1))) void*)g,
        (__attribute__((address_space(3))) void*)l, 16, 0, 0);
}

// ---------------------------------------------------------------------------
// Prep: Wcat f16 gate-interleaved (row-major [p][KC]);
// Woutb f16 frag-blocked LANE-MAJOR (verified round 6 first-launch):
// frag (of,kf) = 1KB at ((of*32+kf)<<9); element (o,k) at lidx*8 + (k&7),
// lidx = ((k>>3)&3)*16 + (o&15)  [MFMA B lane l holds B[n=l&15][k=(l>>4)*8+u]]
// ---------------------------------------------------------------------------
__global__ __launch_bounds__(256) void conv_wcat(
    const float* __restrict__ W_ih, const float* __restrict__ W_hh,
    _Float16* __restrict__ Wcat)
{
    int k = blockIdx.x * 256 + threadIdx.x;
    int p = blockIdx.y;
    int g = (p >> 5) & 3, jt = p >> 7, jr = p & 31;
    int n = g * HH + jt * 32 + jr;
    float v = (k < OO) ? W_ih[(size_t)n * OO + k] : W_hh[(size_t)n * HH + (k - OO)];
    Wcat[(size_t)p * KC + k] = (_Float16)v;
}

__global__ __launch_bounds__(256) void conv_wout(
    const float* __restrict__ W_out, _Float16* __restrict__ Woutb)
{
    int k = blockIdx.x * 256 + threadIdx.x;  // 0..1023
    int o = blockIdx.y;                      // 0..511
    int of = o >> 4, kf = k >> 5;
    int lidx = ((k >> 3) & 3) * 16 + (o & 15);
    int u = k & 7;
    Woutb[((size_t)(of * 32 + kf) << 9) + lidx * 8 + u] =
        (_Float16)W_out[(size_t)o * HH + k];
}

__global__ __launch_bounds__(256) void prep_misc(
    const float* __restrict__ b_ih, const float* __restrict__ b_hh,
    const float* __restrict__ h0, const float* __restrict__ c0,
    float* __restrict__ bias_p, _Float16* __restrict__ xh0, float* __restrict__ cst)
{
    int idx0 = blockIdx.x * blockDim.x + threadIdx.x;
    int stride = gridDim.x * blockDim.x;
    for (int p = idx0; p < G4H; p += stride) {
        int g = (p >> 5) & 3, jt = p >> 7, jr = p & 31;
        int n = g * HH + jt * 32 + jr;
        bias_p[p] = b_ih[n] + b_hh[n];
    }
    for (int i = idx0; i < BB * KC; i += stride) {
        int b = i / KC, q = i - b * KC;
        xh0[i] = (q < OO) ? (_Float16)0.f : (_Float16)h0[b * HH + (q - OO)];
    }
    for (int i = idx0; i < BB * HH; i += stride) cst[i] = c0[i];
}

// ---------------------------------------------------------------------------
// gates: round-3 PROVEN structure — 64b x 128p block-tile, BK=128,
// single-buffered [stage-DMA; barrier; compute; barrier], XOR-swizzled LDS,
// 16x16x32 MFMA, wave-tile 32x64. 256 blocks, XCD-pinned decode:
// XCD j (= blockIdx%8 dispatch heuristic) owns pt in [4j,4j+4) -> its Wcat
// strip (1.6 MB) + A (1.5 MB) stay L2-resident across the K-loop and steps.
// (Round-6 dbuf prefetch-after-barrier reverted: post-timing divergence —
// loop-carried LDS-DMA drain at loop-top barrier is unproven on this backend;
// it also regressed perf. Do not reintroduce without asm evidence.)
// ---------------------------------------------------------------------------
__global__ __launch_bounds__(256) void gates_mfma(
    const _Float16* __restrict__ xh_in,   // [B][KC]
    _Float16* __restrict__ xh_out,        // [B][KC] (h at +OO)
    float* __restrict__ cst,              // [B][H]
    const _Float16* __restrict__ Wcat,    // [4096][KC] permuted
    const float* __restrict__ bias_p)     // [4096] permuted
{
    const int lb = blockIdx.x;            // 0..255
    const int xcd = lb & 7, idx = lb >> 3;
    const int pt = xcd * 4 + (idx & 3);   // 0..31, pinned to XCD
    const int bt = idx >> 2;              // 0..7
    const int p0 = pt * 128, b0 = bt * 64;
    const int tid = threadIdx.x;
    const int l = tid & 63, w = tid >> 6;
    const int wm = w & 1, wn = w >> 1;    // 2(b) x 2(p) waves
    const int l15 = l & 15, l4 = l >> 4;

    __shared__ __align__(16) char smem[49152];
    _Float16* Af = (_Float16*)smem;              // [64][128] (16 KB)
    _Float16* Bf = (_Float16*)(smem + 16384);    // [128][128] (32 KB)

    f32x4 acc[2][4];
    #pragma unroll
    for (int fm = 0; fm < 2; ++fm)
        #pragma unroll
        for (int fn = 0; fn < 4; ++fn)
            acc[fm][fn] = (f32x4){0.f, 0.f, 0.f, 0.f};

    for (int k0 = 0; k0 < KC; k0 += 128) {
        // A: 64 rows x 16 chunks; 16 DMA calls (4/wave, 4 rows each)
        #pragma unroll
        for (int j = 0; j < 4; ++j) {
            int r0 = (w * 4 + j) * 4;
            int row = r0 + l4;                     // l4 in 0..3
            int c = l15 ^ (row & 7);               // XOR-swizzled source chunk
            dma16(&xh_in[(size_t)(b0 + row) * KC + k0 + c * 8],
                  &Af[(size_t)(w * 4 + j) * 512]);
        }
        // B: 128 rows x 16 chunks; 32 DMA calls (8/wave)
        #pragma unroll
        for (int j = 0; j < 8; ++j) {
            int r0 = (w * 8 + j) * 4;
            int row = r0 + l4;
            int c = l15 ^ (row & 7);
            dma16(&Wcat[(size_t)(p0 + row) * KC + k0 + c * 8],
                  &Bf[(size_t)(w * 8 + j) * 512]);
        }
        __syncthreads();   // drains DMAs (vmcnt) before any ds_read

        #pragma unroll
        for (int ks = 0; ks < 4; ++ks) {
            int cc = (ks * 4 + l4) ^ (l15 & 7);    // swizzled chunk slot
            half8 af[2], bfr[4];
            #pragma unroll
            for (int fm = 0; fm < 2; ++fm) {
                int R = wm * 32 + fm * 16 + l15;
                af[fm] = *(const half8*)&Af[R * 128 + cc * 8];
            }
            #pragma unroll
            for (int fn = 0; fn < 4; ++fn) {
                int S = wn * 64 + fn * 16 + l15;
                bfr[fn] = *(const half8*)&Bf[S * 128 + cc * 8];
            }
            #pragma unroll
            for (int fm = 0; fm < 2; ++fm)
                #pragma unroll
                for (int fn = 0; fn < 4; ++fn)
                    acc[fm][fn] = __builtin_amdgcn_mfma_f32_16x16x32_f16(
                        af[fm], bfr[fn], acc[fm][fn], 0, 0, 0);
        }
        __syncthreads();
    }

    // exchange preactivations through LDS (overlay), stride 133 fp32
    float* exch = (float*)smem;   // [64][133]
    #pragma unroll
    for (int fm = 0; fm < 2; ++fm)
        #pragma unroll
        for (int fn = 0; fn < 4; ++fn)
            #pragma unroll
            for (int r = 0; r < 4; ++r) {
                int row = wm * 32 + fm * 16 + l4 * 4 + r;   // batch-local
                int col = wn * 64 + fn * 16 + l15;          // p-local
                exch[row * 133 + col] = acc[fm][fn][r];
            }
    __syncthreads();

    // cell update: thread -> batch-local bl = tid>>2, jr = (tid&3)*8 + u
    int bl = tid >> 2;
    int b = b0 + bl;
    int jbase = (tid & 3) * 8;
    float cv[8], hv[8], cold[8];
    *(float4*)&cold[0] = *(const float4*)&cst[(size_t)b * HH + pt * 32 + jbase];
    *(float4*)&cold[4] = *(const float4*)&cst[(size_t)b * HH + pt * 32 + jbase + 4];
    #pragma unroll
    for (int u = 0; u < 8; ++u) {
        int jr = jbase + u;
        float gi = exch[bl * 133 +       jr] + bias_p[p0 +       jr];
        float gf = exch[bl * 133 + 32 + jr] + bias_p[p0 + 32 + jr];
        float gg = exch[bl * 133 + 64 + jr] + bias_p[p0 + 64 + jr];
        float go = exch[bl * 133 + 96 + jr] + bias_p[p0 + 96 + jr];
        float iv = 1.f / (1.f + expf(-gi));
        float fv = 1.f / (1.f + expf(-gf));
        float gv = tanhf(gg);
        float ov = 1.f / (1.f + expf(-go));
        float cnew = fv * cold[u] + iv * gv;
        cv[u] = cnew;
        hv[u] = ov * tanhf(cnew);
    }
    *(float4*)&cst[(size_t)b * HH + pt * 32 + jbase]     = *(const float4*)&cv[0];
    *(float4*)&cst[(size_t)b * HH + pt * 32 + jbase + 4] = *(const float4*)&cv[4];
    half8 hh;
    #pragma unroll
    for (int u = 0; u < 8; ++u) hh[u] = (_Float16)hv[u];
    *(half8*)&xh_out[(size_t)b * KC + OO + pt * 32 + jbase] = hh;
}

// ---------------------------------------------------------------------------
// fused logits + softmax: 32 blocks x 512 thr; block = 16 batch x all 512 O.
// A (16x1024 f16) staged once in LDS (plain loads, swizzled); B fragments
// read directly from global in lane-major frag-blocked layout (1 KB coalesced
// per frag, no LDS, no inner barriers, disjoint o-strips per wave).
// ---------------------------------------------------------------------------
__global__ __launch_bounds__(512) void logits_softmax(
    const _Float16* __restrict__ xh,      // h at +OO, flat [B][KC]
    const _Float16* __restrict__ Woutb,   // frag-blocked lane-major
    const float* __restrict__ b_out,
    float* __restrict__ out_slice,        // [B][O] fp32 (time slice)
    _Float16* __restrict__ xh_next)       // x part of xh (same buffer as h)
{
    const int b0 = blockIdx.x * 16;
    const int tid = threadIdx.x;          // 0..511
    const int l = tid & 63, w = tid >> 6; // 8 waves, wave w owns o [64w, 64w+64)
    const int l15 = l & 15, l4 = l >> 4;

    __shared__ __align__(16) char smem[33280];
    _Float16* Ast = (_Float16*)smem;      // [16][1024], chunk slot = c ^ (r&7)

    // stage A once
    #pragma unroll
    for (int rep = 0; rep < 4; ++rep) {
        int idxc = rep * 512 + tid;       // 0..2047 chunk id
        int r = idxc >> 7, c = idxc & 127;
        half8 v = *(const half8*)&xh[(size_t)(b0 + r) * KC + OO + c * 8];
        int sl = c ^ (r & 7);
        *(half8*)&Ast[r * 1024 + sl * 8] = v;
    }
    __syncthreads();

    f32x4 acc[4];
    #pragma unroll
    for (int fn = 0; fn < 4; ++fn) acc[fn] = (f32x4){0.f, 0.f, 0.f, 0.f};

    #pragma unroll 2
    for (int kf = 0; kf < 32; ++kf) {
        int cc = (kf * 4 + l4) ^ (l15 & 7);
        half8 a = *(const half8*)&Ast[l15 * 1024 + cc * 8];
        #pragma unroll
        for (int fn = 0; fn < 4; ++fn) {
            int of = w * 4 + fn;
            half8 bq = *(const half8*)&Woutb[((size_t)(of * 32 + kf) << 9) + l * 8];
            acc[fn] = __builtin_amdgcn_mfma_f32_16x16x32_f16(a, bq, acc[fn], 0, 0, 0);
        }
    }

    __syncthreads();                       // done with Ast; reuse as exch
    float* exch = (float*)smem;            // [16][516]
    #pragma unroll
    for (int fn = 0; fn < 4; ++fn) {
        float bo = b_out[w * 64 + fn * 16 + l15];
        #pragma unroll
        for (int r = 0; r < 4; ++r) {
            int row = l4 * 4 + r;
            int col = w * 64 + fn * 16 + l15;
            exch[row * 516 + col] = acc[fn][r] + bo;
        }
    }
    __syncthreads();

    // softmax: wave w handles rows 2w, 2w+1
    #pragma unroll
    for (int q = 0; q < 2; ++q) {
        int rr = w * 2 + q;
        float v[8];
        *(float4*)&v[0] = *(const float4*)&exch[rr * 516 + l * 8];
        *(float4*)&v[4] = *(const float4*)&exch[rr * 516 + l * 8 + 4];
        float m = v[0];
        #pragma unroll
        for (int u = 1; u < 8; ++u) m = fmaxf(m, v[u]);
        #pragma unroll
        for (int off = 1; off < 64; off <<= 1) m = fmaxf(m, __shfl_xor(m, off, 64));
        float s = 0.f;
        #pragma unroll
        for (int u = 0; u < 8; ++u) { v[u] = expf(v[u] - m); s += v[u]; }
        #pragma unroll
        for (int off = 1; off < 64; off <<= 1) s += __shfl_xor(s, off, 64);
        float inv = 1.f / s;
        float y[8];
        half8 hh;
        #pragma unroll
        for (int u = 0; u < 8; ++u) { y[u] = v[u] * inv; hh[u] = (_Float16)y[u]; }
        *(float4*)&out_slice[(size_t)(b0 + rr) * OO + l * 8]     = *(const float4*)&y[0];
        *(float4*)&out_slice[(size_t)(b0 + rr) * OO + l * 8 + 4] = *(const float4*)&y[4];
        *(half8*)&xh_next[(size_t)(b0 + rr) * KC + l * 8] = hh;
    }
}

// ---------------------------------------------------------------------------
extern "C" void kernel_launch(void* const* d_in, const int* in_sizes, int n_in,
                              void* d_out, int out_size, void* d_ws, size_t ws_size,
                              hipStream_t stream)
{
    const float* h0    = (const float*)d_in[0];
    const float* c0    = (const float*)d_in[1];
    const float* W_ih  = (const float*)d_in[2];
    const float* W_hh  = (const float*)d_in[3];
    const float* b_ih  = (const float*)d_in[4];
    const float* b_hh  = (const float*)d_in[5];
    const float* W_out = (const float*)d_in[6];
    const float* b_out = (const float*)d_in[7];
    float* out = (float*)d_out;

    char* wsb = (char*)d_ws;
    _Float16* Wcat   = (_Float16*)wsb;                 wsb += (size_t)G4H * KC * 2;
    _Float16* Woutb  = (_Float16*)wsb;                 wsb += (size_t)OO * HH * 2;
    float*    bias_p = (float*)wsb;                    wsb += (size_t)G4H * 4;
    _Float16* xh0    = (_Float16*)wsb;                 wsb += (size_t)BB * KC * 2;
    _Float16* xh1    = (_Float16*)wsb;                 wsb += (size_t)BB * KC * 2;
    float*    cst    = (float*)wsb;                    wsb += (size_t)BB * HH * 4;

    conv_wcat<<<dim3(KC / 256, G4H), 256, 0, stream>>>(W_ih, W_hh, Wcat);
    conv_wout<<<dim3(HH / 256, OO), 256, 0, stream>>>(W_out, Woutb);
    prep_misc<<<512, 256, 0, stream>>>(b_ih, b_hh, h0, c0, bias_p, xh0, cst);

    for (int t = 0; t < TT; ++t) {
        _Float16* xin  = (t & 1) ? xh1 : xh0;
        _Float16* xout = (t & 1) ? xh0 : xh1;
        gates_mfma<<<256, 256, 0, stream>>>(xin, xout, cst, Wcat, bias_p);
        logits_softmax<<<32, 512, 0, stream>>>(
            xout, Woutb, b_out, out + (size_t)(TT - 1 - t) * BB * OO, xout);
    }
}

// Round 8
// 7310.923 us; speedup vs baseline: 2.0130x; 2.0130x over previous
//
#include <hip/hip_runtime.h>
#include <math.h>

#define BB 512     // batch
#define HH 1024    // hidden
#define OO 512     // output
#define KC 1536    // O + H
#define G4H 4096   // 4*H
#define TT 256     // out_len

typedef _Float16 half8 __attribute__((ext_vector_type(8)));
typedef float f32x4 __attribute__((ext_vector_type(4)));

// async global->LDS DMA, 16B/lane (used by logits staging — proven r3 path)
__device__ __forceinline__ void dma16(const void* g, void* l) {
    __builtin_amdgcn_global_load_lds(
        (const __attribute__((address_space(1))) void*)g,
        (__attribute__((address_space(3))) void*)l, 16, 0, 0);
}

// ---------------------------------------------------------------------------
// Prep: Wcat f16 gate-interleaved (row-major [p][KC]); Wout16 row-major [O][H]
// ---------------------------------------------------------------------------
__global__ __launch_bounds__(256) void conv_wcat(
    const float* __restrict__ W_ih, const float* __restrict__ W_hh,
    _Float16* __restrict__ Wcat)
{
    int k = blockIdx.x * 256 + threadIdx.x;
    int p = blockIdx.y;
    int g = (p >> 5) & 3, jt = p >> 7, jr = p & 31;
    int n = g * HH + jt * 32 + jr;
    float v = (k < OO) ? W_ih[(size_t)n * OO + k] : W_hh[(size_t)n * HH + (k - OO)];
    Wcat[(size_t)p * KC + k] = (_Float16)v;
}

__global__ __launch_bounds__(256) void conv_wout(
    const float* __restrict__ W_out, _Float16* __restrict__ Wout16)
{
    int k = blockIdx.x * 256 + threadIdx.x;  // 0..1023
    int o = blockIdx.y;                      // 0..511
    Wout16[(size_t)o * HH + k] = (_Float16)W_out[(size_t)o * HH + k];
}

__global__ __launch_bounds__(256) void prep_misc(
    const float* __restrict__ b_ih, const float* __restrict__ b_hh,
    const float* __restrict__ h0, const float* __restrict__ c0,
    float* __restrict__ bias_p, _Float16* __restrict__ xh0, float* __restrict__ cst)
{
    int idx0 = blockIdx.x * blockDim.x + threadIdx.x;
    int stride = gridDim.x * blockDim.x;
    for (int p = idx0; p < G4H; p += stride) {
        int g = (p >> 5) & 3, jt = p >> 7, jr = p & 31;
        int n = g * HH + jt * 32 + jr;
        bias_p[p] = b_ih[n] + b_hh[n];
    }
    for (int i = idx0; i < BB * KC; i += stride) {
        int b = i / KC, q = i - b * KC;
        xh0[i] = (q < OO) ? (_Float16)0.f : (_Float16)h0[b * HH + (q - OO)];
    }
    for (int i = idx0; i < BB * HH; i += stride) cst[i] = c0[i];
}

// ---------------------------------------------------------------------------
// gates: 64b x 128p block-tile, BK=128, REGISTER-prefetch double buffering:
//   [sync; ds_write regs(tile k); sync; global_load tile k+1 -> regs; compute k]
// Fragment math / swizzle / epilogue identical to proven round-3 kernel.
// No loop-carried LDS-DMA (round-6 hazard class avoided): prefetch goes to
// VGPRs; its vmcnt wait lands at next iteration's ds_write, after compute
// has overlapped the L2 latency. grid (32 pt, 8 bt) = 256 blocks (r3 mapping;
// dispatch %8 already gives each XCD 4 resident Wcat strips).
// ---------------------------------------------------------------------------
__global__ __launch_bounds__(256) void gates_mfma(
    const _Float16* __restrict__ xh_in,   // [B][KC]
    _Float16* __restrict__ xh_out,        // [B][KC] (h at +OO)
    float* __restrict__ cst,              // [B][H]
    const _Float16* __restrict__ Wcat,    // [4096][KC] permuted
    const float* __restrict__ bias_p)     // [4096] permuted
{
    const int pt = blockIdx.x;
    const int p0 = pt * 128, b0 = blockIdx.y * 64;
    const int tid = threadIdx.x;
    const int l = tid & 63, w = tid >> 6;
    const int wm = w & 1, wn = w >> 1;    // 2(b) x 2(p) waves
    const int l15 = l & 15, l4 = l >> 4;

    __shared__ __align__(16) char smem[49152];
    _Float16* Af = (_Float16*)smem;              // [64][128] (16 KB), slot s of row r = chunk s^(r&7)
    _Float16* Bf = (_Float16*)(smem + 16384);    // [128][128] (32 KB)

    f32x4 acc[2][4];
    #pragma unroll
    for (int fm = 0; fm < 2; ++fm)
        #pragma unroll
        for (int fn = 0; fn < 4; ++fn)
            acc[fm][fn] = (f32x4){0.f, 0.f, 0.f, 0.f};

    half8 ra[4], rb[8];    // staging registers (48 VGPRs)

    auto load_regs = [&](int k0) {
        #pragma unroll
        for (int j = 0; j < 4; ++j) {          // A: row group w*4+j, 4 rows
            int row = (w * 4 + j) * 4 + l4;
            int c = l15 ^ (row & 7);
            ra[j] = *(const half8*)&xh_in[(size_t)(b0 + row) * KC + k0 + c * 8];
        }
        #pragma unroll
        for (int j = 0; j < 8; ++j) {          // B: row group w*8+j
            int row = (w * 8 + j) * 4 + l4;
            int c = l15 ^ (row & 7);
            rb[j] = *(const half8*)&Wcat[(size_t)(p0 + row) * KC + k0 + c * 8];
        }
    };
    auto store_lds = [&]() {
        #pragma unroll
        for (int j = 0; j < 4; ++j)            // mirror of r3 DMA dest: base + l*16B
            *(half8*)&Af[(size_t)(w * 4 + j) * 512 + l * 8] = ra[j];
        #pragma unroll
        for (int j = 0; j < 8; ++j)
            *(half8*)&Bf[(size_t)(w * 8 + j) * 512 + l * 8] = rb[j];
    };

    load_regs(0);
    #pragma unroll 1
    for (int it = 0; it < KC / 128; ++it) {
        __syncthreads();                       // prior compute done reading LDS
        store_lds();                           // (waits vmcnt on ra/rb here)
        __syncthreads();                       // staging visible to all waves
        if (it + 1 < KC / 128) load_regs((it + 1) * 128);   // prefetch, overlaps compute

        #pragma unroll
        for (int ks = 0; ks < 4; ++ks) {
            int cc = (ks * 4 + l4) ^ (l15 & 7);    // swizzled chunk slot
            half8 af[2], bfr[4];
            #pragma unroll
            for (int fm = 0; fm < 2; ++fm) {
                int R = wm * 32 + fm * 16 + l15;
                af[fm] = *(const half8*)&Af[R * 128 + cc * 8];
            }
            #pragma unroll
            for (int fn = 0; fn < 4; ++fn) {
                int S = wn * 64 + fn * 16 + l15;
                bfr[fn] = *(const half8*)&Bf[S * 128 + cc * 8];
            }
            #pragma unroll
            for (int fm = 0; fm < 2; ++fm)
                #pragma unroll
                for (int fn = 0; fn < 4; ++fn)
                    acc[fm][fn] = __builtin_amdgcn_mfma_f32_16x16x32_f16(
                        af[fm], bfr[fn], acc[fm][fn], 0, 0, 0);
        }
    }
    __syncthreads();

    // exchange preactivations through LDS (overlay), stride 133 fp32
    float* exch = (float*)smem;   // [64][133]
    #pragma unroll
    for (int fm = 0; fm < 2; ++fm)
        #pragma unroll
        for (int fn = 0; fn < 4; ++fn)
            #pragma unroll
            for (int r = 0; r < 4; ++r) {
                int row = wm * 32 + fm * 16 + l4 * 4 + r;   // batch-local
                int col = wn * 64 + fn * 16 + l15;          // p-local
                exch[row * 133 + col] = acc[fm][fn][r];
            }
    __syncthreads();

    // cell update: thread -> batch-local bl = tid>>2, jr = (tid&3)*8 + u
    int bl = tid >> 2;
    int b = b0 + bl;
    int jbase = (tid & 3) * 8;
    float cv[8], hv[8], cold[8];
    *(float4*)&cold[0] = *(const float4*)&cst[(size_t)b * HH + pt * 32 + jbase];
    *(float4*)&cold[4] = *(const float4*)&cst[(size_t)b * HH + pt * 32 + jbase + 4];
    #pragma unroll
    for (int u = 0; u < 8; ++u) {
        int jr = jbase + u;
        float gi = exch[bl * 133 +       jr] + bias_p[p0 +       jr];
        float gf = exch[bl * 133 + 32 + jr] + bias_p[p0 + 32 + jr];
        float gg = exch[bl * 133 + 64 + jr] + bias_p[p0 + 64 + jr];
        float go = exch[bl * 133 + 96 + jr] + bias_p[p0 + 96 + jr];
        float iv = 1.f / (1.f + expf(-gi));
        float fv = 1.f / (1.f + expf(-gf));
        float gv = tanhf(gg);
        float ov = 1.f / (1.f + expf(-go));
        float cnew = fv * cold[u] + iv * gv;
        cv[u] = cnew;
        hv[u] = ov * tanhf(cnew);
    }
    *(float4*)&cst[(size_t)b * HH + pt * 32 + jbase]     = *(const float4*)&cv[0];
    *(float4*)&cst[(size_t)b * HH + pt * 32 + jbase + 4] = *(const float4*)&cv[4];
    half8 hh;
    #pragma unroll
    for (int u = 0; u < 8; ++u) hh[u] = (_Float16)hv[u];
    *(half8*)&xh_out[(size_t)b * KC + OO + pt * 32 + jbase] = hh;
}

// ---------------------------------------------------------------------------
// logits: PROVEN round-3 kernel. 32b x 32o tiles, grid (16,16)=256 blocks,
// 128 threads (2 waves), BK=128, DMA staging + swizzle, bias in epilogue.
// ---------------------------------------------------------------------------
__global__ __launch_bounds__(128) void logits_mfma(
    const _Float16* __restrict__ xh,      // h at +OO
    const _Float16* __restrict__ Wout16,  // [O][H]
    const float* __restrict__ b_out,
    float* __restrict__ logits)           // [B][O]
{
    const int o0 = blockIdx.x * 32, b0 = blockIdx.y * 32;
    const int tid = threadIdx.x;
    const int l = tid & 63, w = tid >> 6;  // 2 waves: batch halves
    const int l15 = l & 15, l4 = l >> 4, lo3 = l & 7;

    __shared__ __align__(16) _Float16 Ah[32 * 128];
    __shared__ __align__(16) _Float16 Bo[32 * 128];

    f32x4 acc[2];
    acc[0] = (f32x4){0.f, 0.f, 0.f, 0.f};
    acc[1] = (f32x4){0.f, 0.f, 0.f, 0.f};

    for (int k0 = 0; k0 < HH; k0 += 128) {
        #pragma unroll
        for (int j = 0; j < 4; ++j) {       // A: 32 rows, 8 calls total
            int row = (w * 4 + j) * 4 + l4;
            int c = l15 ^ (row & 7);
            dma16(&xh[(size_t)(b0 + row) * KC + OO + k0 + c * 8],
                  &Ah[(size_t)(w * 4 + j) * 512]);
        }
        #pragma unroll
        for (int j = 0; j < 4; ++j) {       // B: 32 rows (o), 8 calls total
            int row = (w * 4 + j) * 4 + l4;
            int c = l15 ^ (row & 7);
            dma16(&Wout16[(size_t)(o0 + row) * HH + k0 + c * 8],
                  &Bo[(size_t)(w * 4 + j) * 512]);
        }
        __syncthreads();
        #pragma unroll
        for (int ks = 0; ks < 4; ++ks) {
            int cc = (ks * 4 + l4) ^ lo3;
            int R = w * 16 + l15;
            half8 a = *(const half8*)&Ah[R * 128 + cc * 8];
            #pragma unroll
            for (int fn = 0; fn < 2; ++fn) {
                int S = fn * 16 + l15;
                half8 bq = *(const half8*)&Bo[S * 128 + cc * 8];
                acc[fn] = __builtin_amdgcn_mfma_f32_16x16x32_f16(a, bq, acc[fn], 0, 0, 0);
            }
        }
        __syncthreads();
    }
    #pragma unroll
    for (int fn = 0; fn < 2; ++fn)
        #pragma unroll
        for (int r = 0; r < 4; ++r) {
            int row = b0 + w * 16 + l4 * 4 + r;
            int col = o0 + fn * 16 + l15;
            logits[(size_t)row * OO + col] = acc[fn][r] + b_out[col];
        }
}

// ---------------------------------------------------------------------------
// softmax: PROVEN round-3 kernel. One wave per row, shuffle-only.
// grid 128 x 256 threads. logits already include b_out.
// ---------------------------------------------------------------------------
__global__ __launch_bounds__(256) void softmax_kernel(
    const float* __restrict__ logits,
    float* __restrict__ out_slice, _Float16* __restrict__ xh_next)
{
    const int w = threadIdx.x >> 6, l = threadIdx.x & 63;
    const int b = blockIdx.x * 4 + w;
    float v[8];
    *(float4*)&v[0] = *(const float4*)&logits[(size_t)b * OO + l * 8];
    *(float4*)&v[4] = *(const float4*)&logits[(size_t)b * OO + l * 8 + 4];

    float m = v[0];
    #pragma unroll
    for (int u = 1; u < 8; ++u) m = fmaxf(m, v[u]);
    #pragma unroll
    for (int off = 1; off < 64; off <<= 1) m = fmaxf(m, __shfl_xor(m, off, 64));

    float s = 0.f;
    #pragma unroll
    for (int u = 0; u < 8; ++u) { v[u] = expf(v[u] - m); s += v[u]; }
    #pragma unroll
    for (int off = 1; off < 64; off <<= 1) s += __shfl_xor(s, off, 64);

    float inv = 1.f / s;
    float y[8];
    half8 hh;
    #pragma unroll
    for (int u = 0; u < 8; ++u) { y[u] = v[u] * inv; hh[u] = (_Float16)y[u]; }
    *(float4*)&out_slice[(size_t)b * OO + l * 8]     = *(const float4*)&y[0];
    *(float4*)&out_slice[(size_t)b * OO + l * 8 + 4] = *(const float4*)&y[4];
    *(half8*)&xh_next[(size_t)b * KC + l * 8] = hh;
}

// ---------------------------------------------------------------------------
extern "C" void kernel_launch(void* const* d_in, const int* in_sizes, int n_in,
                              void* d_out, int out_size, void* d_ws, size_t ws_size,
                              hipStream_t stream)
{
    const float* h0    = (const float*)d_in[0];
    const float* c0    = (const float*)d_in[1];
    const float* W_ih  = (const float*)d_in[2];
    const float* W_hh  = (const float*)d_in[3];
    const float* b_ih  = (const float*)d_in[4];
    const float* b_hh  = (const float*)d_in[5];
    const float* W_out = (const float*)d_in[6];
    const float* b_out = (const float*)d_in[7];
    float* out = (float*)d_out;

    char* wsb = (char*)d_ws;
    _Float16* Wcat   = (_Float16*)wsb;                 wsb += (size_t)G4H * KC * 2;
    _Float16* Wout16 = (_Float16*)wsb;                 wsb += (size_t)OO * HH * 2;
    float*    bias_p = (float*)wsb;                    wsb += (size_t)G4H * 4;
    _Float16* xh0    = (_Float16*)wsb;                 wsb += (size_t)BB * KC * 2;
    _Float16* xh1    = (_Float16*)wsb;                 wsb += (size_t)BB * KC * 2;
    float*    cst    = (float*)wsb;                    wsb += (size_t)BB * HH * 4;
    float*    logits = (float*)wsb;                    wsb += (size_t)BB * OO * 4;

    conv_wcat<<<dim3(KC / 256, G4H), 256, 0, stream>>>(W_ih, W_hh, Wcat);
    conv_wout<<<dim3(HH / 256, OO), 256, 0, stream>>>(W_out, Wout16);
    prep_misc<<<512, 256, 0, stream>>>(b_ih, b_hh, h0, c0, bias_p, xh0, cst);

    for (int t = 0; t < TT; ++t) {
        _Float16* xin  = (t & 1) ? xh1 : xh0;
        _Float16* xout = (t & 1) ? xh0 : xh1;
        gates_mfma<<<dim3(32, 8), 256, 0, stream>>>(xin, xout, cst, Wcat, bias_p);
        logits_mfma<<<dim3(16, 16), 128, 0, stream>>>(xout, Wout16, b_out, logits);
        softmax_kernel<<<128, 256, 0, stream>>>(
            logits, out + (size_t)(TT - 1 - t) * BB * OO, xout);
    }
}